// Round 1
// baseline (88.990 us; speedup 1.0000x reference)
//
#include <hip/hip_runtime.h>

// Problem: out[b,c] = sum_n exp(-2*r2(n,b)) * exp(-max(t,0)/2) * mem[n,c]
//   n over 128^3 grid (x slowest, z fastest), B=32 rays, C=16 channels.
//   t  = x.d - o.d            (d ~unit, but we keep exact d2 like the reference)
//   r2 = |x|^2 - 2 x.o + |o|^2 - 2 t^2 + t^2 |d|^2

constexpr int BRAYS = 32;
constexpr int CCH   = 16;
constexpr int DGRID = 128;
constexpr int NVOX  = DGRID * DGRID * DGRID;   // 2,097,152
constexpr int TILE  = 256;                     // voxels per block-iteration
constexpr int NTILES = NVOX / TILE;            // 8192
constexpr int NTHR  = 256;
constexpr int NBLK  = 1024;                    // grid-stride: 8 tiles/block

__global__ __launch_bounds__(NTHR)
void hpm_fwd(const float* __restrict__ ray_o,
             const float* __restrict__ ray_d,
             const float* __restrict__ mem,
             float* __restrict__ out)
{
    // kernS padded to 257 floats/row: read addr = b*257+n -> bank (b+n)%32,
    // all 32 distinct across b (conflict-free); writes are lane-consecutive n.
    __shared__ float  kernS[BRAYS][257];     // 32,896 B
    __shared__ float  memS[TILE][CCH];       // 16,384 B
    __shared__ float4 coordS[TILE];          //  4,096 B   (total ~53.4 KB -> 3 blocks/CU)

    const int tid = threadIdx.x;

    // ---------------- phase-1 mapping: one fixed ray per thread ----------------
    const int b1 = tid & 31;      // ray id
    const int g1 = tid >> 5;      // voxel group (32 voxels each)

    const float o0 = ray_o[b1*3+0], o1 = ray_o[b1*3+1], o2 = ray_o[b1*3+2];
    const float dd0 = ray_d[b1*3+0], dd1 = ray_d[b1*3+1], dd2 = ray_d[b1*3+2];
    const float pd = -(o0*dd0 + o1*dd1 + o2*dd2);          // -o.d
    const float oo = o0*o0 + o1*o1 + o2*o2;                // |o|^2
    const float m0 = -2.0f*o0, m1 = -2.0f*o1, m2 = -2.0f*o2;
    const float d2sum = dd0*dd0 + dd1*dd1 + dd2*dd2;
    const float q = 2.0f - d2sum;                          // r2 = w - q*t*t

    // ---------------- phase-2 mapping ----------------
    const int lane = tid & 63;
    const int s  = tid >> 6;      // n-slice 0..3 (64 voxels each)
    const int b2 = lane >> 1;     // ray id 0..31
    const int cg = lane & 1;      // channel group: c in [cg*8, cg*8+8)

    float acc[8];
    #pragma unroll
    for (int j = 0; j < 8; ++j) acc[j] = 0.0f;

    for (int tile = blockIdx.x; tile < NTILES; tile += gridDim.x) {
        // ---- stage mem tile (coalesced float4), overlap with coord compute ----
        const float4* src4 = reinterpret_cast<const float4*>(mem + (size_t)tile * (TILE*CCH));
        float4 stg[4];
        #pragma unroll
        for (int k = 0; k < 4; ++k) stg[k] = src4[tid + NTHR*k];

        {   // voxel coords + |x|^2 for this tile (z fastest, 256 vox = 2 y-rows)
            const int m = tile * TILE + tid;
            const float fx = (float)(m >> 14);
            const float fy = (float)((m >> 7) & 127);
            const float fz = (float)(m & 127);
            coordS[tid] = make_float4(fx, fy, fz, fmaf(fx, fx, fmaf(fy, fy, fz*fz)));
        }

        float4* dst4 = reinterpret_cast<float4*>(&memS[0][0]);
        #pragma unroll
        for (int k = 0; k < 4; ++k) dst4[tid + NTHR*k] = stg[k];

        __syncthreads();

        // ---- phase 1: kern eval, 32 voxels for ray b1 ----
        #pragma unroll 4
        for (int i = 0; i < 32; ++i) {
            const int n = g1*32 + i;
            const float4 cd = coordS[n];   // broadcast across the 32 b-lanes
            const float t  = fmaf(cd.x, dd0, fmaf(cd.y, dd1, fmaf(cd.z, dd2, pd)));
            const float w  = fmaf(cd.x, m0,  fmaf(cd.y, m1,  fmaf(cd.z, m2, cd.w + oo)));
            const float r2 = fmaf(-q*t, t, w);
            const float rt = fmaxf(t, 0.0f);
            kernS[b1][n] = __expf(fmaf(rt, -0.5f, -2.0f*r2));
        }
        __syncthreads();

        // ---- phase 2: outer-product accumulate ----
        #pragma unroll 4
        for (int j = 0; j < 64; ++j) {
            const int n = s*64 + j;
            const float k = kernS[b2][n];
            const float4* mrow = reinterpret_cast<const float4*>(&memS[n][0]);
            const float4 v0 = mrow[cg*2 + 0];
            const float4 v1 = mrow[cg*2 + 1];
            acc[0] = fmaf(k, v0.x, acc[0]);
            acc[1] = fmaf(k, v0.y, acc[1]);
            acc[2] = fmaf(k, v0.z, acc[2]);
            acc[3] = fmaf(k, v0.w, acc[3]);
            acc[4] = fmaf(k, v1.x, acc[4]);
            acc[5] = fmaf(k, v1.y, acc[5]);
            acc[6] = fmaf(k, v1.z, acc[6]);
            acc[7] = fmaf(k, v1.w, acc[7]);
        }
        __syncthreads();   // protect LDS before next tile's overwrite
    }

    // ---- block reduce across the 4 n-slices, then one atomic pass ----
    float* red = &kernS[0][0];                 // reuse: needs 2048 floats
    const int e0 = b2*16 + cg*8;
    float4* redv = reinterpret_cast<float4*>(red + s*512 + e0);
    redv[0] = make_float4(acc[0], acc[1], acc[2], acc[3]);
    redv[1] = make_float4(acc[4], acc[5], acc[6], acc[7]);
    __syncthreads();

    for (int e = tid; e < 512; e += NTHR) {
        const float v = red[e] + red[512 + e] + red[1024 + e] + red[1536 + e];
        atomicAdd(&out[e], v);
    }
}

extern "C" void kernel_launch(void* const* d_in, const int* in_sizes, int n_in,
                              void* d_out, int out_size, void* d_ws, size_t ws_size,
                              hipStream_t stream)
{
    const float* ray_o = (const float*)d_in[0];   // [32,3]
    const float* ray_d = (const float*)d_in[1];   // [32,3]
    const float* mem   = (const float*)d_in[2];   // [128^3,16]
    float* out = (float*)d_out;                   // [32,16]

    hipMemsetAsync(out, 0, 512 * sizeof(float), stream);
    hipLaunchKernelGGL(hpm_fwd, dim3(NBLK), dim3(NTHR), 0, stream,
                       ray_o, ray_d, mem, out);
}

// Round 2
// 15.412 us; speedup vs baseline: 5.7739x; 5.7739x over previous
//
#include <hip/hip_runtime.h>
#include <math.h>

// out[b,c] = sum_n exp(-2*r2(n,b)) * exp(-max(t,0)/2) * mem[n,c]
// Culled version: kern <= exp(-(2 r2 + max(t,0)/2)); drop when arg < -20
// (exp(-20) ~ 2e-9). Relevant voxels form a radius-~3.2 tube around each
// ray line (decaying forward past t~40). March the dominant axis; per
// integer plane the tube cross-section has in-plane radius
// <= 3.17/|d_dom| <= 3.17*sqrt(3) ~ 5.5 (+1 rounding) -> a 16x16 box
// centered on the line crossing covers it exactly.

constexpr int BRAYS  = 32;
constexpr int DGRID  = 128;
constexpr int NCHUNK = 16;                 // plane-chunks per ray
constexpr int PLANES = DGRID / NCHUNK;     // 8 planes per block
constexpr int NTHR   = 256;

__global__ __launch_bounds__(NTHR)
void hpm_tube(const float* __restrict__ ray_o,
              const float* __restrict__ ray_d,
              const float* __restrict__ mem,
              float* __restrict__ out)
{
    const int tid   = threadIdx.x;
    const int b     = blockIdx.x & (BRAYS - 1);
    const int chunk = blockIdx.x >> 5;
    const int k0    = chunk * PLANES;

    // ---- ray setup (wave-uniform) ----
    const float ox = ray_o[b*3+0], oy = ray_o[b*3+1], oz = ray_o[b*3+2];
    const float dx = ray_d[b*3+0], dy = ray_d[b*3+1], dz = ray_d[b*3+2];
    const float ax = fabsf(dx), ay = fabsf(dy), az = fabsf(dz);

    int a;                                   // dominant axis
    if (ax >= ay && ax >= az) a = 0; else if (ay >= az) a = 1; else a = 2;
    const int p1 = (a == 0) ? 1 : 0;
    const int p2 = (a == 2) ? 1 : 2;

    const float o3[3] = {ox, oy, oz};
    const float d3[3] = {dx, dy, dz};
    const int   st[3] = {DGRID * DGRID * 16, DGRID * 16, 16};  // float strides

    const float oa = o3[a],  da = d3[a];
    const float o1 = o3[p1], d1 = d3[p1];
    const float o2 = o3[p2], d2 = d3[p2];
    const int   sa = st[a],  s1 = st[p1], s2 = st[p2];
    const float inv_da = 1.0f / da;
    const float q = 2.0f - (dx*dx + dy*dy + dz*dz);   // r2 = |e|^2 - q*t^2

    // ---- thread's in-plane box offset ----
    const int u = tid >> 4;    // 0..15 along p1
    const int v = tid & 15;    // 0..15 along p2

    float acc[16];
    #pragma unroll
    for (int c = 0; c < 16; ++c) acc[c] = 0.0f;

    #pragma unroll
    for (int i = 0; i < PLANES; ++i) {
        const int   k  = k0 + i;
        const float tk = ((float)k - oa) * inv_da;     // t at plane crossing
        if (tk > 46.0f) continue;                      // forward decay: all arg < -20

        const float yc = o1 + tk * d1;
        const float zc = o2 + tk * d2;
        const int y = (int)floorf(yc) - 7 + u;
        const int z = (int)floorf(zc) - 7 + v;

        const float e0 = (float)k - oa;
        const float e1 = (float)y - o1;
        const float e2 = (float)z - o2;
        const float t   = fmaf(e0, da, fmaf(e1, d1, e2 * d2));
        const float ee  = fmaf(e0, e0, fmaf(e1, e1, e2 * e2));
        const float r2  = fmaf(-q * t, t, ee);
        const float arg = fmaf(fmaxf(t, 0.0f), -0.5f, -2.0f * r2);

        if (arg > -20.0f && ((unsigned)y < 128u) && ((unsigned)z < 128u)) {
            const float w = __expf(arg);
            const float4* row = reinterpret_cast<const float4*>(
                mem + (size_t)k * sa + (size_t)y * s1 + (size_t)z * s2);
            const float4 m0 = row[0], m1 = row[1], m2 = row[2], m3 = row[3];
            acc[ 0] = fmaf(w, m0.x, acc[ 0]); acc[ 1] = fmaf(w, m0.y, acc[ 1]);
            acc[ 2] = fmaf(w, m0.z, acc[ 2]); acc[ 3] = fmaf(w, m0.w, acc[ 3]);
            acc[ 4] = fmaf(w, m1.x, acc[ 4]); acc[ 5] = fmaf(w, m1.y, acc[ 5]);
            acc[ 6] = fmaf(w, m1.z, acc[ 6]); acc[ 7] = fmaf(w, m1.w, acc[ 7]);
            acc[ 8] = fmaf(w, m2.x, acc[ 8]); acc[ 9] = fmaf(w, m2.y, acc[ 9]);
            acc[10] = fmaf(w, m2.z, acc[10]); acc[11] = fmaf(w, m2.w, acc[11]);
            acc[12] = fmaf(w, m3.x, acc[12]); acc[13] = fmaf(w, m3.y, acc[13]);
            acc[14] = fmaf(w, m3.z, acc[14]); acc[15] = fmaf(w, m3.w, acc[15]);
        }
    }

    // ---- block tree-reduction in LDS (256 x 16 floats = 16 KB) ----
    __shared__ float4 red[NTHR][4];
    const float4* accv = reinterpret_cast<const float4*>(acc);
    red[tid][0] = accv[0]; red[tid][1] = accv[1];
    red[tid][2] = accv[2]; red[tid][3] = accv[3];
    __syncthreads();

    #pragma unroll
    for (int s = NTHR / 2; s > 0; s >>= 1) {
        if (tid < s) {
            #pragma unroll
            for (int c = 0; c < 4; ++c) {
                const float4 x = red[tid + s][c];
                float4 y4 = red[tid][c];
                y4.x += x.x; y4.y += x.y; y4.z += x.z; y4.w += x.w;
                red[tid][c] = y4;
            }
        }
        __syncthreads();
    }

    if (tid < 16) {
        const float* r0 = reinterpret_cast<const float*>(&red[0][0]);
        atomicAdd(&out[b * 16 + tid], r0[tid]);
    }
}

extern "C" void kernel_launch(void* const* d_in, const int* in_sizes, int n_in,
                              void* d_out, int out_size, void* d_ws, size_t ws_size,
                              hipStream_t stream)
{
    const float* ray_o = (const float*)d_in[0];   // [32,3]
    const float* ray_d = (const float*)d_in[1];   // [32,3]
    const float* mem   = (const float*)d_in[2];   // [128^3,16]
    float* out = (float*)d_out;                   // [32,16]

    hipMemsetAsync(out, 0, 512 * sizeof(float), stream);
    hipLaunchKernelGGL(hpm_tube, dim3(BRAYS * NCHUNK), dim3(NTHR), 0, stream,
                       ray_o, ray_d, mem, out);
}

// Round 3
// 11.918 us; speedup vs baseline: 7.4667x; 1.2932x over previous
//
#include <hip/hip_runtime.h>
#include <math.h>

// out[b,c] = sum_n exp(-2*r2(n,b)) * exp(-max(t,0)/2) * mem[n,c]
// Tube-culled: kern <= exp(arg), arg = -2*r2 - max(t,0)/2; drop arg < -20
// (exp(-20) ~ 2e-9). March dominant axis; per integer plane the relevant
// cross-section has in-plane radius <= 3.17/|d_a| <= 3.17*sqrt(3) ~ 5.5
// (+1 rounding) -> 16x16 box centered on the line crossing covers it.
// t > 46 planes culled: within the box |t - tk| <= ~3.2, so arg < -20 there.

constexpr int BRAYS  = 32;
constexpr int DGRID  = 128;
constexpr int NCHUNK = 32;                 // plane-chunks per ray
constexpr int PLANES = DGRID / NCHUNK;     // 4 planes per block
constexpr int NTHR   = 256;
constexpr int NBLK   = BRAYS * NCHUNK;     // 1024 blocks

__global__ __launch_bounds__(NTHR)
void hpm_tube(const float* __restrict__ ray_o,
              const float* __restrict__ ray_d,
              const float* __restrict__ mem,
              float* __restrict__ part)   // [BRAYS][NCHUNK][16]
{
    const int tid   = threadIdx.x;
    const int b     = blockIdx.x & (BRAYS - 1);
    const int chunk = blockIdx.x >> 5;
    const int k0    = chunk * PLANES;

    // ---- ray setup (wave-uniform) ----
    const float ox = ray_o[b*3+0], oy = ray_o[b*3+1], oz = ray_o[b*3+2];
    const float dx = ray_d[b*3+0], dy = ray_d[b*3+1], dz = ray_d[b*3+2];
    const float ax = fabsf(dx), ay = fabsf(dy), az = fabsf(dz);

    int a;                                   // dominant axis
    if (ax >= ay && ax >= az) a = 0; else if (ay >= az) a = 1; else a = 2;
    const int p1 = (a == 0) ? 1 : 0;
    const int p2 = (a == 2) ? 1 : 2;

    const float o3[3] = {ox, oy, oz};
    const float d3[3] = {dx, dy, dz};
    const int   st[3] = {DGRID * DGRID * 16, DGRID * 16, 16};  // float strides

    const float oa = o3[a],  da = d3[a];
    const float o1 = o3[p1], d1 = d3[p1];
    const float o2 = o3[p2], d2 = d3[p2];
    const int   sa = st[a],  s1 = st[p1], s2 = st[p2];
    const float inv_da = 1.0f / da;
    const float q = 2.0f - (dx*dx + dy*dy + dz*dz);   // r2 = |e|^2 - q*t^2

    // ---- thread's in-plane box offset ----
    const int u = tid >> 4;    // 0..15 along p1
    const int v = tid & 15;    // 0..15 along p2

    float acc[16];
    #pragma unroll
    for (int c = 0; c < 16; ++c) acc[c] = 0.0f;

    #pragma unroll
    for (int i = 0; i < PLANES; ++i) {
        const int   k  = k0 + i;
        const float tk = ((float)k - oa) * inv_da;     // t at plane crossing
        if (tk > 46.0f) continue;                      // forward decay: all arg < -20

        const float yc = o1 + tk * d1;
        const float zc = o2 + tk * d2;
        const int y = (int)floorf(yc) - 7 + u;
        const int z = (int)floorf(zc) - 7 + v;

        const float e0 = (float)k - oa;
        const float e1 = (float)y - o1;
        const float e2 = (float)z - o2;
        const float t   = fmaf(e0, da, fmaf(e1, d1, e2 * d2));
        const float ee  = fmaf(e0, e0, fmaf(e1, e1, e2 * e2));
        const float r2  = fmaf(-q * t, t, ee);
        const float arg = fmaf(fmaxf(t, 0.0f), -0.5f, -2.0f * r2);

        if (arg > -20.0f && ((unsigned)y < 128u) && ((unsigned)z < 128u)) {
            const float w = __expf(arg);
            const float4* row = reinterpret_cast<const float4*>(
                mem + (size_t)k * sa + (size_t)y * s1 + (size_t)z * s2);
            const float4 m0 = row[0], m1 = row[1], m2 = row[2], m3 = row[3];
            acc[ 0] = fmaf(w, m0.x, acc[ 0]); acc[ 1] = fmaf(w, m0.y, acc[ 1]);
            acc[ 2] = fmaf(w, m0.z, acc[ 2]); acc[ 3] = fmaf(w, m0.w, acc[ 3]);
            acc[ 4] = fmaf(w, m1.x, acc[ 4]); acc[ 5] = fmaf(w, m1.y, acc[ 5]);
            acc[ 6] = fmaf(w, m1.z, acc[ 6]); acc[ 7] = fmaf(w, m1.w, acc[ 7]);
            acc[ 8] = fmaf(w, m2.x, acc[ 8]); acc[ 9] = fmaf(w, m2.y, acc[ 9]);
            acc[10] = fmaf(w, m2.z, acc[10]); acc[11] = fmaf(w, m2.w, acc[11]);
            acc[12] = fmaf(w, m3.x, acc[12]); acc[13] = fmaf(w, m3.y, acc[13]);
            acc[14] = fmaf(w, m3.z, acc[14]); acc[15] = fmaf(w, m3.w, acc[15]);
        }
    }

    // ---- wave fold-reduction: halve register count each step ----
    // After step m: lane's kept channel index gains bit (lane&m ? half : 0).
    // Final: lane holds channel brev4(lane&15), summed over its 16-lane group.
    const int lane = tid & 63;
    float r[16];
    #pragma unroll
    for (int c = 0; c < 16; ++c) r[c] = acc[c];

#define FOLD(MASK, HALF)                                        \
    {                                                           \
        const bool hi = (lane & (MASK)) != 0;                   \
        _Pragma("unroll")                                       \
        for (int i = 0; i < (HALF); ++i) {                      \
            const float give = hi ? r[i] : r[i + (HALF)];       \
            const float keep = hi ? r[i + (HALF)] : r[i];       \
            r[i] = keep + __shfl_xor(give, (MASK), 64);         \
        }                                                       \
    }
    FOLD(1, 8)
    FOLD(2, 4)
    FOLD(4, 2)
    FOLD(8, 1)
#undef FOLD
    float sum = r[0];
    sum += __shfl_xor(sum, 16, 64);
    sum += __shfl_xor(sum, 32, 64);
    // channel this lane holds:
    const int l4 = lane & 15;
    const int ch = ((l4 & 1) << 3) | ((l4 & 2) << 1) | ((l4 & 4) >> 1) | ((l4 & 8) >> 3);

    // ---- cross-wave combine (4 waves) ----
    __shared__ float ws[4][16];
    if (lane < 16) ws[tid >> 6][ch] = sum;
    __syncthreads();

    if (tid < 16) {
        const float p = ws[0][tid] + ws[1][tid] + ws[2][tid] + ws[3][tid];
        part[(b * NCHUNK + chunk) * 16 + tid] = p;
    }
}

// part[b][k][c] summed over k -> out[b][c]; 128 threads, each owns (b, c-group)
__global__ __launch_bounds__(128)
void hpm_reduce(const float* __restrict__ part, float* __restrict__ out)
{
    const int tid = threadIdx.x;
    const int b   = tid >> 2;          // 0..31
    const int cg  = tid & 3;           // float4 group 0..3

    float4 s = make_float4(0.f, 0.f, 0.f, 0.f);
    #pragma unroll
    for (int k = 0; k < NCHUNK; ++k) {
        const float4 v = reinterpret_cast<const float4*>(
            part + (size_t)(b * NCHUNK + k) * 16)[cg];
        s.x += v.x; s.y += v.y; s.z += v.z; s.w += v.w;
    }
    reinterpret_cast<float4*>(out + b * 16)[cg] = s;
}

extern "C" void kernel_launch(void* const* d_in, const int* in_sizes, int n_in,
                              void* d_out, int out_size, void* d_ws, size_t ws_size,
                              hipStream_t stream)
{
    const float* ray_o = (const float*)d_in[0];   // [32,3]
    const float* ray_d = (const float*)d_in[1];   // [32,3]
    const float* mem   = (const float*)d_in[2];   // [128^3,16]
    float* out  = (float*)d_out;                  // [32,16]
    float* part = (float*)d_ws;                   // [32][32][16] = 64 KB

    hipLaunchKernelGGL(hpm_tube, dim3(NBLK), dim3(NTHR), 0, stream,
                       ray_o, ray_d, mem, part);
    hipLaunchKernelGGL(hpm_reduce, dim3(1), dim3(128), 0, stream,
                       part, out);
}